// Round 2
// baseline (198.551 us; speedup 1.0000x reference)
//
#include <hip/hip_runtime.h>
#include <stdint.h>
#include <stddef.h>

// GA3 conv2d == one dense 3x3 conv with sign-permuted weights:
//   out[b, c*8+m, h, w] = bias_eff[c*8+m]
//     + sum_{cin,k,kh,kw} s(m,k) * W[j(m,k),c,cin,kh,kw] * x[b, cin*8+k, h+kh-1, w+kw-1]
// bf16 MFMA implicit GEMM over 9 taps (K=128 each).
// R2: zero-barrier K-loop (B-fragments direct from L2-resident global in fragment
// order), XOR-swizzled lds_x (kills the 16-way b128 conflict), border kernel
// instead of 34.6 MB memset.

typedef __attribute__((ext_vector_type(8))) short short8;   // 8 x bf16 (4 VGPRs)
typedef __attribute__((ext_vector_type(4))) float f32x4;    // MFMA accumulator

// j(m,k) and s(m,k): unique j with S[m,j,k]!=0, transcribed from _TERMS.
__device__ __constant__ int c_J[64] = {
  0,1,2,3,4,5,6,7,
  1,0,4,6,2,7,3,5,
  2,4,0,5,1,3,7,6,
  3,6,5,0,7,2,1,4,
  4,2,1,7,0,6,5,3,
  5,7,3,2,6,0,4,1,
  6,3,7,1,5,4,0,2,
  7,5,6,4,3,1,2,0
};
__device__ __constant__ float c_Sg[64] = {
  1,1,1,1,-1,-1,-1,-1,
  1,1,-1,-1,1,-1,1,-1,
  1,1,1,-1,-1,1,1,1,
  1,1,1,1,-1,-1,-1,-1,
  1,1,-1,1,1,1,-1,1,
  1,1,1,-1,-1,1,1,1,
  1,1,-1,-1,1,-1,1,-1,
  1,1,-1,1,1,1,-1,1
};

__device__ inline unsigned short f2bf(float f) {  // RNE float->bf16
  unsigned int u = __float_as_uint(f);
  u += 0x7FFFu + ((u >> 16) & 1u);
  return (unsigned short)(u >> 16);
}

// ---------------- Prep A: x [8][128][128][128] f32 NCHW -> xt [8][130][130][128] bf16 NHWC (interior) ---
__global__ __launch_bounds__(256) void xpose_kernel(const float* __restrict__ x,
                                                    unsigned short* __restrict__ xt) {
  __shared__ unsigned short t[128 * 33];  // [ic][w], stride 33 kills bank conflicts
  const int wt  = blockIdx.x;       // 0..3  (tile of 32 w)
  const int h   = blockIdx.y;       // 0..127
  const int b   = blockIdx.z;       // 0..7
  const int tid = threadIdx.x;
  const int w0  = wt * 32;
  const int wl  = tid & 31;
  const int ic0 = tid >> 5;         // 0..7
  #pragma unroll
  for (int i = 0; i < 16; ++i) {    // read coalesced along w
    int ic = ic0 + i * 8;
    float v = x[((size_t)(b * 128 + ic) * 128 + h) * 128 + w0 + wl];
    t[ic * 33 + wl] = f2bf(v);
  }
  __syncthreads();
  #pragma unroll
  for (int i = 0; i < 8; ++i) {     // write coalesced along ic
    int q = tid + i * 256;          // 0..2047 = 32 w * 64 ic-pairs
    int w = q >> 6;
    int p = q & 63;
    unsigned int lo = t[(2 * p) * 33 + w];
    unsigned int hi = t[(2 * p + 1) * 33 + w];
    size_t off = ((size_t)(b * 130 + h + 1) * 130 + (w0 + w + 1)) * 128 + 2 * p;
    *(unsigned int*)(xt + off) = lo | (hi << 16);
  }
}

// ---------------- Border zero: rows 0/129 (130 px) + cols 0/129 (128 px) per b -> 516 px * 128 ic ----
__global__ __launch_bounds__(256) void border_kernel(unsigned short* __restrict__ xt) {
  const int b = blockIdx.y;
  #pragma unroll
  for (int i = 0; i < 4; ++i) {
    int c = (blockIdx.x * 4 + i) * 256 + threadIdx.x;   // chunk id, 16B each
    if (c >= 516 * 16) continue;
    int p = c >> 4, unit = c & 15;
    int row, col;
    if (p < 130)      { row = 0;        col = p; }
    else if (p < 260) { row = 129;      col = p - 130; }
    else if (p < 388) { row = p - 259;  col = 0; }       // rows 1..128
    else              { row = p - 387;  col = 129; }
    size_t off16 = ((size_t)(b * 130 + row) * 130 + col) * 16 + unit;
    ((uint4*)xt)[off16] = uint4{0u, 0u, 0u, 0u};
  }
}

// ---------------- Prep B: vt in B-fragment order [t][half][kc][nt][lane][8j] + bias_eff[128] --------
// B-frag for MFMA 16x16x32: lane = quad*16+l15 holds B[k=quad*8+j][n=l15].
__global__ __launch_bounds__(256) void wprep_kernel(const float* __restrict__ W,
                                                    const float* __restrict__ bias,
                                                    unsigned short* __restrict__ vt,
                                                    float* __restrict__ beff) {
  int gid = blockIdx.x * 256 + threadIdx.x;   // 9*128*128 = 147456 threads exactly
  int t   = gid >> 14;
  int rem = gid & 16383;
  int oc  = rem >> 7;
  int ic  = rem & 127;
  int m = oc & 7, cout = oc >> 3;
  int k = ic & 7, cin = ic >> 3;
  int j = c_J[m * 8 + k];
  float s = c_Sg[m * 8 + k];
  float val = s * W[((j * 16 + cout) * 16 + cin) * 9 + t];
  int half = ic >> 6, kc = (ic >> 5) & 1, quad = (ic >> 3) & 3, jj = ic & 7;
  int nt = oc >> 4, l15 = oc & 15;
  int lane = quad * 16 + l15;
  vt[(size_t)((((t * 2 + half) * 2 + kc) * 8 + nt) * 64 + lane) * 8 + jj] = f2bf(val);
  if (gid < 128) {
    int m2 = gid & 7, cout2 = gid >> 3;
    float acc = 0.f;
    #pragma unroll
    for (int kk = 0; kk < 8; ++kk)
      acc += c_Sg[m2 * 8 + kk] * bias[c_J[m2 * 8 + kk] * 16 + cout2];
    beff[gid] = acc;
  }
}

// ---------------- Main: tap-decomposed implicit GEMM, bf16 MFMA 16x16x32, zero-barrier K-loop -------
// Block: 256 thr = 4 waves. Tile: 8 rows x 16 cols of pixels x 128 oc.
// lds_x XOR-swizzle: 16B unit u (0..15 within a 128-short pixel) stored at
// u' = (u&8) | ((u ^ (pixel&7)) & 7). Spreads b128 fragment reads over all banks.
__global__ __launch_bounds__(256, 3) void conv_kernel(const unsigned short* __restrict__ xt,
                                                      const unsigned short* __restrict__ vt,
                                                      const float* __restrict__ beff,
                                                      float* __restrict__ out) {
  __shared__ __align__(16) unsigned short lds_x[10 * 18 * 128]; // 45 KiB, swizzled
  const int tid  = threadIdx.x;
  const int bx   = blockIdx.x;    // 0..7   w tile (16)
  const int by   = blockIdx.y;    // 0..15  h tile (8)
  const int b    = blockIdx.z;    // 0..7
  const int lane = tid & 63;
  const int wave = tid >> 6;
  const int wm   = wave >> 1;     // 0..1  row half
  const int wn   = wave & 1;      // 0..1  oc half
  const int l15  = lane & 15;
  const int quad = lane >> 4;
  const int h0 = by * 8, w0 = bx * 16;

  // Stage x halo tile: rows h0..h0+9, cols w0..w0+17, 128 ic = 2880 x 16B chunks, swizzled.
  {
    #pragma unroll
    for (int i = 0; i < 12; ++i) {
      int c = tid + i * 256;
      if (c < 2880) {
        int hh = c / 288;               // 288 chunks per halo row (18 px * 16 units)
        int r  = c - hh * 288;
        int ww = r >> 4, u = r & 15;
        int p  = hh * 18 + ww;
        int up = (u & 8) | ((u ^ p) & 7);
        const uint4* src = (const uint4*)(xt + ((size_t)(b * 130 + h0 + hh) * 130 + w0) * 128) + r;
        ((uint4*)lds_x)[p * 16 + up] = *src;
      }
    }
  }
  __syncthreads();

  f32x4 acc[4][4];
  #pragma unroll
  for (int mi = 0; mi < 4; ++mi)
    #pragma unroll
    for (int ni = 0; ni < 4; ++ni)
      acc[mi][ni] = f32x4{0.f, 0.f, 0.f, 0.f};

  #pragma unroll
  for (int t = 0; t < 9; ++t) {
    const int dh = t / 3, dw = t % 3;
    int prow[4], key[4];
    #pragma unroll
    for (int mi = 0; mi < 4; ++mi) {
      int p = (wm * 4 + mi + dh) * 18 + l15 + dw;   // pixel index in halo tile
      prow[mi] = p * 128;
      key[mi]  = p & 7;
    }
    #pragma unroll
    for (int half = 0; half < 2; ++half) {
      // B-fragments straight from global (L2-resident, coalesced 1 KB per load)
      short8 bb[8];
      #pragma unroll
      for (int kc = 0; kc < 2; ++kc)
        #pragma unroll
        for (int ni = 0; ni < 4; ++ni)
          bb[kc * 4 + ni] = *(const short8*)(vt +
              (size_t)((((t * 2 + half) * 2 + kc) * 8 + (wn * 4 + ni)) * 64 + lane) * 8);
      #pragma unroll
      for (int kc = 0; kc < 2; ++kc) {
        short8 a[4];
        #pragma unroll
        for (int mi = 0; mi < 4; ++mi) {
          int up = half * 8 + ((kc * 4 + quad) ^ key[mi]);
          a[mi] = *(const short8*)(lds_x + prow[mi] + up * 8);
        }
        #pragma unroll
        for (int mi = 0; mi < 4; ++mi)
          #pragma unroll
          for (int ni = 0; ni < 4; ++ni)
            acc[mi][ni] = __builtin_amdgcn_mfma_f32_16x16x32_bf16(a[mi], bb[kc * 4 + ni], acc[mi][ni], 0, 0, 0);
      }
    }
  }

  // Epilogue: D row = quad*4+reg (pixel w offset), col = l15 (oc). float4 stores, w-contiguous.
  #pragma unroll
  for (int ni = 0; ni < 4; ++ni) {
    int oc = (wn * 4 + ni) * 16 + l15;
    float bv = beff[oc];
    #pragma unroll
    for (int mi = 0; mi < 4; ++mi) {
      int h = h0 + wm * 4 + mi;
      int w = w0 + quad * 4;
      f32x4 v = acc[mi][ni];
      v[0] += bv; v[1] += bv; v[2] += bv; v[3] += bv;
      *(f32x4*)(out + ((size_t)(b * 128 + oc) * 128 + h) * 128 + w) = v;
    }
  }
}

extern "C" void kernel_launch(void* const* d_in, const int* in_sizes, int n_in,
                              void* d_out, int out_size, void* d_ws, size_t ws_size,
                              hipStream_t stream) {
  (void)in_sizes; (void)n_in; (void)out_size; (void)ws_size;
  const float* x    = (const float*)d_in[0];   // [8][128][128][128]
  const float* W    = (const float*)d_in[1];   // [8][16][16][3][3]
  const float* bias = (const float*)d_in[2];   // [8][16]
  float* out = (float*)d_out;                  // [8][128][128][128]

  const size_t XT_BYTES = (size_t)8 * 130 * 130 * 128 * 2;   // 34,611,200
  const size_t VT_BYTES = (size_t)9 * 2 * 128 * 64 * 2;      //    294,912
  unsigned short* xt = (unsigned short*)d_ws;
  unsigned short* vt = (unsigned short*)((char*)d_ws + XT_BYTES);
  float* beff = (float*)((char*)d_ws + XT_BYTES + VT_BYTES);

  border_kernel<<<dim3(9, 8), 256, 0, stream>>>(xt);          // zero padding border only (~1 MB)
  xpose_kernel<<<dim3(4, 128, 8), 256, 0, stream>>>(x, xt);
  wprep_kernel<<<dim3(576), 256, 0, stream>>>(W, bias, vt, beff);
  conv_kernel<<<dim3(8, 16, 8), 256, 0, stream>>>(xt, vt, beff, out);
}

// Round 3
// 193.830 us; speedup vs baseline: 1.0244x; 1.0244x over previous
//
#include <hip/hip_runtime.h>
#include <stdint.h>
#include <stddef.h>

// GA3 conv2d == one dense 3x3 conv with sign-permuted weights:
//   out[b, c*8+m, h, w] = bias_eff[c*8+m]
//     + sum_{cin,k,kh,kw} s(m,k) * W[j(m,k),c,cin,kh,kw] * x[b, cin*8+k, h+kh-1, w+kw-1]
// bf16 MFMA implicit GEMM over 9 taps (K=128 each).
// R3: tile 4h x 32w so each 128B output line is fully written by ONE wave
// (kills the R2 partial-line RFO/write-amplification: WRITE 164MB -> ~66MB),
// zero-barrier K-loop kept, XOR-swizzled lds_x kept, border fused into xpose.

typedef __attribute__((ext_vector_type(8))) short short8;   // 8 x bf16 (4 VGPRs)
typedef __attribute__((ext_vector_type(4))) float f32x4;    // MFMA accumulator

// j(m,k) and s(m,k): unique j with S[m,j,k]!=0, transcribed from _TERMS.
__device__ __constant__ int c_J[64] = {
  0,1,2,3,4,5,6,7,
  1,0,4,6,2,7,3,5,
  2,4,0,5,1,3,7,6,
  3,6,5,0,7,2,1,4,
  4,2,1,7,0,6,5,3,
  5,7,3,2,6,0,4,1,
  6,3,7,1,5,4,0,2,
  7,5,6,4,3,1,2,0
};
__device__ __constant__ float c_Sg[64] = {
  1,1,1,1,-1,-1,-1,-1,
  1,1,-1,-1,1,-1,1,-1,
  1,1,1,-1,-1,1,1,1,
  1,1,1,1,-1,-1,-1,-1,
  1,1,-1,1,1,1,-1,1,
  1,1,1,-1,-1,1,1,1,
  1,1,-1,-1,1,-1,1,-1,
  1,1,-1,1,1,1,-1,1
};

__device__ inline unsigned short f2bf(float f) {  // RNE float->bf16
  unsigned int u = __float_as_uint(f);
  u += 0x7FFFu + ((u >> 16) & 1u);
  return (unsigned short)(u >> 16);
}

// ---- Prep A (fused): by<128: x NCHW f32 -> xt [8][130][130][128] bf16 NHWC; by==128: zero border ----
__global__ __launch_bounds__(256) void xpose_kernel(const float* __restrict__ x,
                                                    unsigned short* __restrict__ xt) {
  const int b   = blockIdx.z;
  const int tid = threadIdx.x;
  if (blockIdx.y == 128) {          // border: 516 px * 16 chunks = 8256 chunks per b, 4 blocks
    #pragma unroll
    for (int i = 0; i < 9; ++i) {
      int c = blockIdx.x * 256 + tid + i * 1024;
      if (c >= 8256) continue;
      int p = c >> 4, unit = c & 15;
      int row, col;
      if (p < 130)      { row = 0;        col = p; }
      else if (p < 260) { row = 129;      col = p - 130; }
      else if (p < 388) { row = p - 259;  col = 0; }       // rows 1..128
      else              { row = p - 387;  col = 129; }
      ((uint4*)xt)[((size_t)(b * 130 + row) * 130 + col) * 16 + unit] = uint4{0u,0u,0u,0u};
    }
    return;
  }
  __shared__ unsigned short t[128 * 33];  // [ic][w], stride 33 kills bank conflicts
  const int wt  = blockIdx.x;       // 0..3  (tile of 32 w)
  const int h   = blockIdx.y;       // 0..127
  const int w0  = wt * 32;
  const int wl  = tid & 31;
  const int ic0 = tid >> 5;         // 0..7
  #pragma unroll
  for (int i = 0; i < 16; ++i) {    // read coalesced along w
    int ic = ic0 + i * 8;
    float v = x[((size_t)(b * 128 + ic) * 128 + h) * 128 + w0 + wl];
    t[ic * 33 + wl] = f2bf(v);
  }
  __syncthreads();
  #pragma unroll
  for (int i = 0; i < 8; ++i) {     // write coalesced along ic
    int q = tid + i * 256;          // 0..2047 = 32 w * 64 ic-pairs
    int w = q >> 6;
    int p = q & 63;
    unsigned int lo = t[(2 * p) * 33 + w];
    unsigned int hi = t[(2 * p + 1) * 33 + w];
    size_t off = ((size_t)(b * 130 + h + 1) * 130 + (w0 + w + 1)) * 128 + 2 * p;
    *(unsigned int*)(xt + off) = lo | (hi << 16);
  }
}

// ---------------- Prep B: vt in B-fragment order [t][half][kc][nt][lane][8j] + bias_eff[128] --------
__global__ __launch_bounds__(256) void wprep_kernel(const float* __restrict__ W,
                                                    const float* __restrict__ bias,
                                                    unsigned short* __restrict__ vt,
                                                    float* __restrict__ beff) {
  int gid = blockIdx.x * 256 + threadIdx.x;   // 9*128*128 = 147456 threads exactly
  int t   = gid >> 14;
  int rem = gid & 16383;
  int oc  = rem >> 7;
  int ic  = rem & 127;
  int m = oc & 7, cout = oc >> 3;
  int k = ic & 7, cin = ic >> 3;
  int j = c_J[m * 8 + k];
  float s = c_Sg[m * 8 + k];
  float val = s * W[((j * 16 + cout) * 16 + cin) * 9 + t];
  int half = ic >> 6, kc = (ic >> 5) & 1, quad = (ic >> 3) & 3, jj = ic & 7;
  int nt = oc >> 4, l15 = oc & 15;
  int lane = quad * 16 + l15;
  vt[(size_t)((((t * 2 + half) * 2 + kc) * 8 + nt) * 64 + lane) * 8 + jj] = f2bf(val);
  if (gid < 128) {
    int m2 = gid & 7, cout2 = gid >> 3;
    float acc = 0.f;
    #pragma unroll
    for (int kk = 0; kk < 8; ++kk)
      acc += c_Sg[m2 * 8 + kk] * bias[c_J[m2 * 8 + kk] * 16 + cout2];
    beff[gid] = acc;
  }
}

// ---------------- Main: tap-decomposed implicit GEMM, bf16 MFMA 16x16x32, zero-barrier K-loop -------
// Block: 256 thr = 4 waves. Tile: 4 rows x 32 cols of pixels x 128 oc.
// m-tiles: 8 (4 h x 2 w-halves). Wave (wm,wn): h rows {wm*2, wm*2+1} x both w-halves
// (4 m-tiles, FULL 32-w lines) x 4 n-tiles (64 oc). 64 f32 acc regs.
// lds_x XOR-swizzle: 16B unit u stored at u' = (u&8) | ((u ^ (pixel&7)) & 7).
__global__ __launch_bounds__(256, 3) void conv_kernel(const unsigned short* __restrict__ xt,
                                                      const unsigned short* __restrict__ vt,
                                                      const float* __restrict__ beff,
                                                      float* __restrict__ out) {
  __shared__ __align__(16) unsigned short lds_x[6 * 34 * 128]; // 51 KiB halo, swizzled
  const int tid  = threadIdx.x;
  const int bx   = blockIdx.x;    // 0..3   w tile (32)
  const int by   = blockIdx.y;    // 0..31  h tile (4)
  const int b    = blockIdx.z;    // 0..7
  const int lane = tid & 63;
  const int wave = tid >> 6;
  const int wm   = wave >> 1;     // 0..1  row pair
  const int wn   = wave & 1;      // 0..1  oc half
  const int l15  = lane & 15;
  const int quad = lane >> 4;
  const int h0 = by * 4, w0 = bx * 32;

  // Stage x halo: padded rows h0..h0+5, cols w0..w0+33, 128 ic = 3264 x 16B chunks, swizzled.
  {
    #pragma unroll
    for (int i = 0; i < 13; ++i) {
      int c = tid + i * 256;
      if (c < 3264) {
        int hh = c / 544;               // 544 chunks per halo row (34 px * 16 units)
        int r  = c - hh * 544;
        int ww = r >> 4, u = r & 15;
        int p  = hh * 34 + ww;
        int up = (u & 8) | ((u ^ p) & 7);
        const uint4* src = (const uint4*)(xt + ((size_t)(b * 130 + h0 + hh) * 130 + w0) * 128) + r;
        ((uint4*)lds_x)[p * 16 + up] = *src;
      }
    }
  }
  __syncthreads();

  f32x4 acc[4][4];
  #pragma unroll
  for (int mi = 0; mi < 4; ++mi)
    #pragma unroll
    for (int ni = 0; ni < 4; ++ni)
      acc[mi][ni] = f32x4{0.f, 0.f, 0.f, 0.f};

  #pragma unroll
  for (int t = 0; t < 9; ++t) {
    const int dh = t / 3, dw = t % 3;
    int prow[4], key[4];
    #pragma unroll
    for (int mi = 0; mi < 4; ++mi) {    // mi = r*2 + w16: r = h offset, w16 = w half
      int p = (wm * 2 + (mi >> 1) + dh) * 34 + ((mi & 1) * 16 + l15 + dw);
      prow[mi] = p * 128;
      key[mi]  = p & 7;
    }
    #pragma unroll
    for (int half = 0; half < 2; ++half) {
      short8 bb[8];                     // B-frags straight from global (L2-resident, 1 KB/load)
      #pragma unroll
      for (int kc = 0; kc < 2; ++kc)
        #pragma unroll
        for (int ni = 0; ni < 4; ++ni)
          bb[kc * 4 + ni] = *(const short8*)(vt +
              (size_t)((((t * 2 + half) * 2 + kc) * 8 + (wn * 4 + ni)) * 64 + lane) * 8);
      #pragma unroll
      for (int kc = 0; kc < 2; ++kc) {
        short8 a[4];
        #pragma unroll
        for (int mi = 0; mi < 4; ++mi) {
          int up = half * 8 + ((kc * 4 + quad) ^ key[mi]);
          a[mi] = *(const short8*)(lds_x + prow[mi] + up * 8);
        }
        #pragma unroll
        for (int mi = 0; mi < 4; ++mi)
          #pragma unroll
          for (int ni = 0; ni < 4; ++ni)
            acc[mi][ni] = __builtin_amdgcn_mfma_f32_16x16x32_bf16(a[mi], bb[kc * 4 + ni], acc[mi][ni], 0, 0, 0);
      }
    }
  }

  // Epilogue: wave writes FULL 128B lines: for (oc, h): w0+quad*4 (w16=0) and w0+16+quad*4 (w16=1).
  #pragma unroll
  for (int ni = 0; ni < 4; ++ni) {
    int oc = (wn * 4 + ni) * 16 + l15;
    float bv = beff[oc];
    #pragma unroll
    for (int r = 0; r < 2; ++r) {
      int h = h0 + wm * 2 + r;
      float* line = out + ((size_t)(b * 128 + oc) * 128 + h) * 128 + w0;
      #pragma unroll
      for (int w16 = 0; w16 < 2; ++w16) {
        f32x4 v = acc[r * 2 + w16][ni];
        v[0] += bv; v[1] += bv; v[2] += bv; v[3] += bv;
        *(f32x4*)(line + w16 * 16 + quad * 4) = v;
      }
    }
  }
}

extern "C" void kernel_launch(void* const* d_in, const int* in_sizes, int n_in,
                              void* d_out, int out_size, void* d_ws, size_t ws_size,
                              hipStream_t stream) {
  (void)in_sizes; (void)n_in; (void)out_size; (void)ws_size;
  const float* x    = (const float*)d_in[0];   // [8][128][128][128]
  const float* W    = (const float*)d_in[1];   // [8][16][16][3][3]
  const float* bias = (const float*)d_in[2];   // [8][16]
  float* out = (float*)d_out;                  // [8][128][128][128]

  const size_t XT_BYTES = (size_t)8 * 130 * 130 * 128 * 2;   // 34,611,200
  const size_t VT_BYTES = (size_t)9 * 2 * 128 * 64 * 2;      //    294,912
  unsigned short* xt = (unsigned short*)d_ws;
  unsigned short* vt = (unsigned short*)((char*)d_ws + XT_BYTES);
  float* beff = (float*)((char*)d_ws + XT_BYTES + VT_BYTES);

  xpose_kernel<<<dim3(4, 129, 8), 256, 0, stream>>>(x, xt);   // by==128 blocks zero the border
  wprep_kernel<<<dim3(576), 256, 0, stream>>>(W, bias, vt, beff);
  conv_kernel<<<dim3(4, 32, 8), 256, 0, stream>>>(xt, vt, beff, out);
}